// Round 8
// baseline (408.177 us; speedup 1.0000x reference)
//
#include <hip/hip_runtime.h>
#include <math.h>

#define N_GRD 4
#define M_SAT 32
#define C_CH  32
#define HK    64
#define WK    64
#define HO    65
#define WO    65
#define SAMPLE_ELEMS (C_CH * HK * WK)

typedef _Float16 h8 __attribute__((ext_vector_type(8)));
typedef float    f4 __attribute__((ext_vector_type(4)));
typedef unsigned int u32;

// ---- ws layout (float units) ----
#define OFF_INV    0
#define OFF_S      64                 // 32 * 4225
#define OFF_CANDV  135264
#define OFF_CANDI  135776
#define OFF_DOTS   136288             // 512
#define OFF_PART   136800             // 32 m * 4 n * 80 xsl * 80 y = 819200 (atomic)
#define OFF_FRAG   956000             // 12,582,912 halfs = 25.2 MB
#define FRAG_GRANULES 1572864         // 12 jg * 8 cq * 64 i * 4 n * 64 lane
#define FRAG_BLOCKS   6144
#define PREP_BLOCKS (FRAG_BLOCKS + M_SAT + N_GRD)

// ---------------------------------------------------------------------------
// K1 (fused prep), by blockIdx range:
//  [0,6144)   frag build: B in MFMA-fragment layout, one 16B granule/thread.
//             frag[jg][cq][i][n][lane]: 8 halfs [q2][c4],
//             value = grd[n][cq*4+c][i][j],  j = jg*8-16+2u-s+q2  (0 outside),
//             s=lane&15, u=lane>>4.  Lane-contiguous => coalesced 1KB/wave.
//  [6144,6176) per-m SAT of s2 (+ sat inv-norm from last prefix entry)
//  [6176,6180) grd inv-norms
// ---------------------------------------------------------------------------
__global__ __launch_bounds__(256) void prep_kernel(const float* __restrict__ grd,
                                                   const float* __restrict__ sat,
                                                   _Float16* __restrict__ frag,
                                                   float* __restrict__ S,
                                                   float* __restrict__ inv) {
    const int bx = blockIdx.x;
    const int tid = threadIdx.x;
    __shared__ float s2[64][65];

    if (bx < FRAG_BLOCKS) {
        int idx = bx * 256 + tid;
        int lane = idx & 63; int t = idx >> 6;
        int n = t & 3; t >>= 2;
        int i = t & 63; t >>= 6;
        int cq = t & 7; int jg = t >> 3;
        int s = lane & 15, u = lane >> 4;
        int jb = jg * 8 - 16 + 2 * u - s;
        const float* gb = grd + ((size_t)n * 32 + cq * 4) * 4096 + i * 64;
        h8 hv = {0, 0, 0, 0, 0, 0, 0, 0};
#pragma unroll
        for (int q2 = 0; q2 < 2; ++q2) {
            int j = jb + q2;
            if (j >= 0 && j < 64) {
#pragma unroll
                for (int c = 0; c < 4; ++c)
                    hv[q2 * 4 + c] = (_Float16)gb[c * 4096 + j];
            }
        }
        *(h8*)(frag + (size_t)idx * 8) = hv;
        return;
    }
    if (bx < FRAG_BLOCKS + M_SAT) {
        const int m = bx - FRAG_BLOCKS;
        const float* base = sat + (size_t)m * SAMPLE_ELEMS;
        for (int p = tid; p < HK * WK; p += 256) {
            float s = 0.0f;
            for (int c = 0; c < C_CH; ++c) {
                float v = base[c * (HK * WK) + p];
                s += v * v;
            }
            s2[p >> 6][p & 63] = s;
        }
        __syncthreads();
        if (tid < 64) {
            int r = tid; float run = 0.0f;
            for (int w = 0; w < 64; ++w) { run += s2[r][w]; s2[r][w] = run; }
        }
        __syncthreads();
        if (tid < 64) {
            int c = tid; float run = 0.0f;
            for (int h = 0; h < 64; ++h) { run += s2[h][c]; s2[h][c] = run; }
        }
        __syncthreads();
        if (tid == 0)
            inv[N_GRD + m] = 1.0f / fmaxf(sqrtf(s2[63][63]), 1e-12f);
        float* Sm = S + (size_t)m * (HO * WO);
        for (int p = tid; p < HO * WO; p += 256) {
            int r = p / 65, c = p - r * 65;
            Sm[p] = (r == 0 || c == 0) ? 0.0f : s2[r - 1][c - 1];
        }
        return;
    }
    {   // grd norms
        const int b = bx - FRAG_BLOCKS - M_SAT;
        const float4* v = reinterpret_cast<const float4*>(grd + (size_t)b * SAMPLE_ELEMS);
        float ss = 0.0f;
        for (int p = tid; p < SAMPLE_ELEMS / 4; p += 256) {
            float4 q = v[p];
            ss += q.x * q.x + q.y * q.y + q.z * q.z + q.w * q.w;
        }
        for (int off = 32; off > 0; off >>= 1) ss += __shfl_down(ss, off);
        __shared__ float ls[4];
        int lane = tid & 63, w = tid >> 6;
        if (lane == 0) ls[w] = ss;
        __syncthreads();
        if (tid == 0)
            inv[b] = 1.0f / fmaxf(sqrtf(ls[0] + ls[1] + ls[2] + ls[3]), 1e-12f);
    }
}

// ---------------------------------------------------------------------------
// K2: MFMA correlation, BARRIER-FREE inner loop.  Grid (m=32, xs=5, z=8:
// h=z&1, qt=z>>1); 4 waves = i-quarters; 3 blocks/CU (LDS 48.4KB).
// A (sat fp16) staged in LDS per cqi (VALU cvt; 2 barriers per cqi only).
// B read directly from global frag tensor: per (wave,ii,qs,n) one coalesced
// lane-contiguous 1KB h8 load; jg = qs + 5h + (xs<4 ? 2 : 0).
// xs=4 uses x00=64 (x slots 64..79; only x=64 kept) so all x-offsets are
// jg-integral — no xoff variants in frag.
// 5 y-tiles (t=4 row0 == y64, rows 1..15 garbage) x 4 n.
// Output: fp32 atomicAdd into partial[m][n][xsl80][y80] (xsl == x).
// ---------------------------------------------------------------------------
__global__ __launch_bounds__(256, 3) void corr_mfma_kernel(const float* __restrict__ sat,
                                                           const _Float16* __restrict__ frag,
                                                           float* __restrict__ partial) {
    __shared__ __align__(16) char AB[48384];   // 43008 A + 5376 garbage pad

    const int m  = blockIdx.x;
    const int xs = blockIdx.y;
    const int z  = blockIdx.z;
    const int h  = z & 1;
    const int qt = z >> 1;

    const int qb     = (xs < 4) ? 16 * xs : 48;
    const int qstage = qb + 40 * h;
    const int qoff   = 5 * h + ((xs < 4) ? 2 : 0);

    const int tid  = threadIdx.x;
    const int w    = tid >> 6;
    const int lane = tid & 63;
    const int s    = lane & 15;
    const int u    = lane >> 4;

    f4 acc[5][4];
#pragma unroll
    for (int t = 0; t < 5; ++t)
#pragma unroll
        for (int n = 0; n < 4; ++n) { acc[t][n][0]=0.f; acc[t][n][1]=0.f; acc[t][n][2]=0.f; acc[t][n][3]=0.f; }

    const int abase0 = s * 336 + u * 16;
    const char* fragB = (const char*)frag;

    for (int cqi = 0; cqi < 2; ++cqi) {
        const int cq = qt * 2 + cqi;
        __syncthreads();  // prior readers of AB done
        // ---- stage A: 128 padded rows x 21 granules (g==20 stride pad)
        for (int k = 0; k < 11; ++k) {
            int idx = k * 256 + tid;
            if (idx < 2688) {
                int r = idx / 21;
                int g = idx - r * 21;
                int q = qstage + 2 * g;
                h8 hv = {0, 0, 0, 0, 0, 0, 0, 0};
                if (g < 20 && r >= 32 && r < 96 && q >= 32 && q < 96) {
                    const float* sp = sat + (((size_t)(m * 32 + cq * 4)) * 64 + (r - 32)) * 64 + (q - 32);
                    float2 v0 = *(const float2*)(sp);
                    float2 v1 = *(const float2*)(sp + 4096);
                    float2 v2 = *(const float2*)(sp + 8192);
                    float2 v3 = *(const float2*)(sp + 12288);
                    hv[0] = (_Float16)v0.x; hv[1] = (_Float16)v1.x; hv[2] = (_Float16)v2.x; hv[3] = (_Float16)v3.x;
                    hv[4] = (_Float16)v0.y; hv[5] = (_Float16)v1.y; hv[6] = (_Float16)v2.y; hv[7] = (_Float16)v3.y;
                }
                *(h8*)(AB + idx * 16) = hv;
            }
        }
        __syncthreads();  // A ready
        // per-wave global B base for this (cq): granule (((jg*8+cq)*64+i)*4+n)*64+lane
        const char* bq0 = fragB + ((size_t)(qoff * 8 + cq) * 64 + w * 16) * 4096 + lane * 16;
        for (int ii = 0; ii < 16; ++ii) {
            const char* Ab = AB + abase0 + (w * 16 + ii) * 336;
            const char* Bq = bq0 + ii * 4096;
#pragma unroll
            for (int qs = 0; qs < 5; ++qs) {
                h8 a[5]; h8 bfr[4];
#pragma unroll
                for (int n = 0; n < 4; ++n)
                    bfr[n] = *(const h8*)(Bq + (size_t)qs * 2097152 + n * 1024);
#pragma unroll
                for (int t = 0; t < 5; ++t) a[t] = *(const h8*)(Ab + qs * 64 + t * 5376);
#pragma unroll
                for (int t = 0; t < 5; ++t)
#pragma unroll
                    for (int n = 0; n < 4; ++n)
                        acc[t][n] = __builtin_amdgcn_mfma_f32_16x16x32_f16(a[t], bfr[n], acc[t][n], 0, 0, 0);
            }
        }
    }

    // ---- cross-wave (i) reduce in LDS, then atomicAdd into partial
    float* red = (float*)AB;
#pragma unroll
    for (int t = 0; t < 5; ++t) {
        __syncthreads();
#pragma unroll
        for (int nn = 0; nn < 4; ++nn)
            *(f4*)(red + ((nn * 4 + w) * 64 + lane) * 4) = acc[t][nn];
        __syncthreads();
        {
            int nn = tid >> 6, ln = tid & 63;
            f4 sum = *(f4*)(red + ((nn * 4 + 0) * 64 + ln) * 4);
            sum = sum + *(f4*)(red + ((nn * 4 + 1) * 64 + ln) * 4);
            sum = sum + *(f4*)(red + ((nn * 4 + 2) * 64 + ln) * 4);
            sum = sum + *(f4*)(red + ((nn * 4 + 3) * 64 + ln) * 4);
            int ss = ln & 15, uu = ln >> 4;
            float* dst = partial + ((size_t)(m * 4 + nn)) * 6400
                         + (xs * 16 + ss) * 80 + t * 16 + uu * 4;
#pragma unroll
            for (int l = 0; l < 4; ++l) atomicAdd(dst + l, sum[l]);
        }
    }
}

// ---------------------------------------------------------------------------
// K3: normalize + top-4 candidates per (m,n).  xsl == x now (xs=4 at x00=64).
// ---------------------------------------------------------------------------
__global__ __launch_bounds__(256) void epilogue_kernel(const float* __restrict__ partial,
                                                       const float* __restrict__ S,
                                                       const float* __restrict__ inv,
                                                       const int* __restrict__ unc,
                                                       float* __restrict__ candv,
                                                       int* __restrict__ candi) {
    const int b = blockIdx.x;
    const int m = b >> 2, n = b & 3;
    const int tid = threadIdx.x;
    const float uu = (float)unc[0];
    const float sc = inv[n] * inv[N_GRD + m];
    const float isn = inv[N_GRD + m];
    const float* Sm = S + (size_t)m * 4225;
    const float* pb = partial + (size_t)(m * 4 + n) * 6400;

    float best = -3.4e38f;
    int bidx = 0x7fffffff;
    for (int pp = tid; pp < 4225; pp += 256) {
        int x = pp / 65, y = pp - x * 65;
        float raw = pb[x * 80 + y];
        float num = raw * sc;
        int r0 = max(0, y - 32), r1 = min(64, y + 32);
        int q0 = max(0, x - 32), q1 = min(64, x + 32);
        float ps = Sm[r1 * 65 + q1] - Sm[r0 * 65 + q1] - Sm[r1 * 65 + q0] + Sm[r0 * 65 + q0];
        float denom = fmaxf(sqrtf(ps) * isn * uu, 1e-12f);
        float v = num / denom;
        int p = y * 65 + x;
        if (v > best || (v == best && p < bidx)) { best = v; bidx = p; }
    }
    __shared__ float bv[256]; __shared__ int bi[256];
    __shared__ float cv[256]; __shared__ int ci[256];
    __shared__ int winner;
    bv[tid] = best; bi[tid] = bidx;
    __syncthreads();
    for (int round = 0; round < 4; ++round) {
        cv[tid] = bv[tid]; ci[tid] = bi[tid];
        __syncthreads();
        for (int st = 128; st > 0; st >>= 1) {
            if (tid < st) {
                float ov = cv[tid + st]; int oi = ci[tid + st];
                if (ov > cv[tid] || (ov == cv[tid] && oi < ci[tid])) { cv[tid] = ov; ci[tid] = oi; }
            }
            __syncthreads();
        }
        if (tid == 0) { candv[b * 4 + round] = cv[0]; candi[b * 4 + round] = ci[0]; winner = ci[0]; }
        __syncthreads();
        if (bi[tid] == winner) bv[tid] = -3.4e38f;
        __syncthreads();
    }
}

// ---------------------------------------------------------------------------
// K4a: exact fp32 dot for candidate (b,k), split over 8 c-chunks (grid z).
// ---------------------------------------------------------------------------
__global__ __launch_bounds__(256) void refine_dot_kernel(const float* __restrict__ grd,
                                                         const float* __restrict__ sat,
                                                         const float* __restrict__ candv,
                                                         const int* __restrict__ candi,
                                                         float* __restrict__ dots) {
    const int b = blockIdx.x;
    const int k = blockIdx.y;
    const int cq = blockIdx.z;
    const int m = b >> 2, n = b & 3;
    float v0 = candv[b * 4];
    float thr = v0 - (0.02f * fabsf(v0) + 1e-4f);
    if (k > 0 && candv[b * 4 + k] < thr) return;   // dots stays 0 (memset)
    int p = candi[b * 4 + k];
    int y = p / 65, x = p - y * 65;
    const int tid = threadIdx.x, lane = tid & 63, w = tid >> 6;
    const int ilo = max(0, 32 - y), ihi = min(64, 96 - y);
    int xj = x + lane - 32;
    float acc = 0.0f;
    if (xj >= 0 && xj < 64) {
        const float* sm = sat + (size_t)m * SAMPLE_ELEMS;
        const float* gn = grd + (size_t)n * SAMPLE_ELEMS;
        for (int cc = 0; cc < 4; ++cc) {
            const int cbase = (cq * 4 + cc) << 12;
            const float* sp = sm + cbase + xj + ((y - 32) << 6);
            const float* gp = gn + cbase + lane;
            for (int i = ilo + w; i < ihi; i += 4)
                acc = fmaf(sp[i << 6], gp[i << 6], acc);
        }
    }
    for (int off = 32; off > 0; off >>= 1) acc += __shfl_down(acc, off);
    __shared__ float ls[4];
    if (lane == 0) ls[w] = acc;
    __syncthreads();
    if (tid == 0) atomicAdd(&dots[b * 4 + k], ls[0] + ls[1] + ls[2] + ls[3]);
}

// ---------------------------------------------------------------------------
// K4b: pick best refined candidate per (m,n), write outputs.  1 block.
// ---------------------------------------------------------------------------
__global__ __launch_bounds__(128) void refine_pick_kernel(const float* __restrict__ S,
                                                          const float* __restrict__ inv,
                                                          const int* __restrict__ unc,
                                                          const float* __restrict__ candv,
                                                          const int* __restrict__ candi,
                                                          const float* __restrict__ dots,
                                                          float* __restrict__ out) {
    int b = threadIdx.x;
    if (b >= 128) return;
    const int m = b >> 2, n = b & 3;
    const float uu = (float)unc[0];
    const float sc = inv[n] * inv[N_GRD + m];
    const float isn = inv[N_GRD + m];
    const float* Sm = S + (size_t)m * 4225;
    float v0 = candv[b * 4];
    float thr = v0 - (0.02f * fabsf(v0) + 1e-4f);
    float bestv = -3.4e38f; int bestp = 0x7fffffff;
    for (int k = 0; k < 4; ++k) {
        if (k > 0 && candv[b * 4 + k] < thr) break;   // candv sorted desc
        int p = candi[b * 4 + k];
        int y = p / 65, x = p - y * 65;
        int r0 = max(0, y - 32), r1 = min(64, y + 32);
        int q0 = max(0, x - 32), q1 = min(64, x + 32);
        float ps = Sm[r1 * 65 + q1] - Sm[r0 * 65 + q1] - Sm[r1 * 65 + q0] + Sm[r0 * 65 + q0];
        float denom = fmaxf(sqrtf(ps) * isn * uu, 1e-12f);
        float v = dots[b * 4 + k] * sc / denom;
        if (v > bestv || (v == bestv && p < bestp)) { bestv = v; bestp = p; }
    }
    out[b] = bestv;
    int row = bestp / 65, col = bestp - row * 65;
    float pr = -((float)row - 32.5f);
    float pc = (float)col - 32.5f;
    out[128 + b * 2 + 0] = ((pr * 0.2f) * 512.0f) * (1.0f / 128.0f);
    out[128 + b * 2 + 1] = ((pc * 0.2f) * 512.0f) * (1.0f / 128.0f);
}

// ---------------------------------------------------------------------------
extern "C" void kernel_launch(void* const* d_in, const int* in_sizes, int n_in,
                              void* d_out, int out_size, void* d_ws, size_t ws_size,
                              hipStream_t stream) {
    const float* grd = (const float*)d_in[0];
    const float* sat = (const float*)d_in[1];
    const int*   unc = (const int*)d_in[2];
    float* out = (float*)d_out;
    float* ws  = (float*)d_ws;

    float* inv     = ws + OFF_INV;
    float* S       = ws + OFF_S;
    float* candv   = ws + OFF_CANDV;
    int*   candi   = (int*)(ws + OFF_CANDI);
    float* dots    = ws + OFF_DOTS;
    float* partial = ws + OFF_PART;
    _Float16* frag = (_Float16*)(ws + OFF_FRAG);  // ~27.6 MB total ws use

    hipMemsetAsync(partial, 0, 819200 * sizeof(float), stream);
    hipMemsetAsync(dots, 0, 512 * sizeof(float), stream);
    prep_kernel<<<PREP_BLOCKS, 256, 0, stream>>>(grd, sat, frag, S, inv);
    corr_mfma_kernel<<<dim3(M_SAT, 5, 8), 256, 0, stream>>>(sat, frag, partial);
    epilogue_kernel<<<M_SAT * N_GRD, 256, 0, stream>>>(partial, S, inv, unc, candv, candi);
    refine_dot_kernel<<<dim3(128, 4, 8), 256, 0, stream>>>(grd, sat, candv, candi, dots);
    refine_pick_kernel<<<1, 128, 0, stream>>>(S, inv, unc, candv, candi, dots, out);
}